// Round 1
// baseline (302.031 us; speedup 1.0000x reference)
//
#include <hip/hip_runtime.h>
#include <math.h>

#define N 1024
#define M 128

// ---------------- transpose D (1024x1024) ----------------
__global__ __launch_bounds__(256) void k_transpose_d(const float* __restrict__ D,
                                                     float* __restrict__ DT) {
  __shared__ float tile[32][33];
  int tx = threadIdx.x, ty = threadIdx.y;
  int bx = blockIdx.x * 32, by = blockIdx.y * 32;
#pragma unroll
  for (int i = 0; i < 4; i++)
    tile[ty + i * 8][tx] = D[(by + ty + i * 8) * N + bx + tx];
  __syncthreads();
#pragma unroll
  for (int i = 0; i < 4; i++)
    DT[(bx + ty + i * 8) * N + by + tx] = tile[tx][ty + i * 8];
}

// ---------------- transpose small weight matrices ----------------
__global__ void k_prep_w(const float* __restrict__ W3A1, const float* __restrict__ W3A2,
                         const float* __restrict__ W3B, const float* __restrict__ W4B,
                         float* __restrict__ oA1, float* __restrict__ oA2,
                         float* __restrict__ oB, float* __restrict__ o4B) {
  const float* in; float* out; int cols;
  if (blockIdx.x == 0)      { in = W3A1; out = oA1; cols = 129; }
  else if (blockIdx.x == 1) { in = W3A2; out = oA2; cols = 129; }
  else if (blockIdx.x == 2) { in = W3B;  out = oB;  cols = 128; }
  else                      { in = W4B;  out = o4B; cols = 256; }
  int total = 128 * cols;
  for (int e = threadIdx.x; e < total; e += blockDim.x) {
    int r = e / cols, c = e % cols;
    out[c * 128 + r] = in[e];  // out[c][r], stride 128
  }
}

// ---------------- block reductions ----------------
__device__ __forceinline__ float blk_max(float v, float* red) {
#pragma unroll
  for (int o = 32; o; o >>= 1) v = fmaxf(v, __shfl_xor(v, o));
  __syncthreads();
  if ((threadIdx.x & 63) == 0) red[threadIdx.x >> 6] = v;
  __syncthreads();
  return fmaxf(fmaxf(red[0], red[1]), fmaxf(red[2], red[3]));
}
__device__ __forceinline__ float blk_sum(float v, float* red) {
#pragma unroll
  for (int o = 32; o; o >>= 1) v += __shfl_xor(v, o);
  __syncthreads();
  if ((threadIdx.x & 63) == 0) red[threadIdx.x >> 6] = v;
  __syncthreads();
  return red[0] + red[1] + red[2] + red[3];
}

// ---------------- edge scores + dual softmax + wd ----------------
// Block v: g[u] = G_raw[u,v] = sum_k W1[k]*relu(D[u,v]*W2[k,0]+dd[u]*W2[k,1]+dd[v]*W2[k,2])
// G_scaled = g/1000 exactly (relu is positively homogeneous).
// PT1[v][u] = softmax_u(g/1000/TAU), PT2[v][u] = softmax_u(g/TAU), diag masked.
// wd1[v] = sum_u PT1 * D[u,v], wd2 likewise.
__global__ __launch_bounds__(256) void k_edge(const float* __restrict__ DT,
                                              const float* __restrict__ dd,
                                              const float* __restrict__ W1,
                                              const float* __restrict__ W2,
                                              float* __restrict__ PT1, float* __restrict__ PT2,
                                              float* __restrict__ wd1, float* __restrict__ wd2) {
  __shared__ float4 wp[128];
  __shared__ float red[4];
  int t = threadIdx.x, v = blockIdx.x;
  if (t < 128) {
    float4 p;
    p.x = W2[t * 3 + 0]; p.y = W2[t * 3 + 1]; p.z = W2[t * 3 + 2]; p.w = W1[t];
    wp[t] = p;
  }
  __syncthreads();
  float yv = dd[v];
  float x[4], z[4], g[4] = {0.f, 0.f, 0.f, 0.f};
#pragma unroll
  for (int i = 0; i < 4; i++) {
    int u = t + i * 256;
    x[i] = DT[v * N + u];
    z[i] = dd[u];
  }
#pragma unroll 2
  for (int k = 0; k < 128; k++) {
    float4 wk = wp[k];
    float cv = yv * wk.z;
#pragma unroll
    for (int i = 0; i < 4; i++) {
      float h = fmaf(x[i], wk.x, fmaf(z[i], wk.y, cv));
      g[i] = fmaf(fmaxf(h, 0.f), wk.w, g[i]);
    }
  }
#pragma unroll
  for (int i = 0; i < 4; i++)
    if (t + i * 256 == v) g[i] = -INFINITY;

  float m = fmaxf(fmaxf(g[0], g[1]), fmaxf(g[2], g[3]));
  m = blk_max(m, red);
  float er[4], es[4], sr = 0.f, ss = 0.f;
#pragma unroll
  for (int i = 0; i < 4; i++) {
    er[i] = expf((g[i] - m) * 0.1f);     // raw: /TAU
    es[i] = expf((g[i] - m) * 1e-4f);    // scaled: /(1000*TAU)
    sr += er[i]; ss += es[i];
  }
  sr = blk_sum(sr, red);
  ss = blk_sum(ss, red);
  float ir = 1.f / sr, is = 1.f / ss;
  float a1 = 0.f, a2 = 0.f;
#pragma unroll
  for (int i = 0; i < 4; i++) {
    int u = t + i * 256;
    float pr = er[i] * ir, ps = es[i] * is;
    PT2[v * N + u] = pr;
    PT1[v * N + u] = ps;
    a1 += ps * x[i];
    a2 += pr * x[i];
  }
  a1 = blk_sum(a1, red);
  a2 = blk_sum(a2, red);
  if (t == 0) { wd1[v] = a1; wd2[v] = a2; }
}

// ---------------- split-K GEMM: C_part[kc] = PT[rows, kchunk] @ mu[kchunk, :] ----------------
// grid (64, 4, nz): 16 rows/block, K-chunk 256, z selects chain.
__global__ __launch_bounds__(256) void k_gemm(const float* __restrict__ PT0, const float* __restrict__ mu_0, float* __restrict__ C_0,
                                              const float* __restrict__ PT1p, const float* __restrict__ mu_1, float* __restrict__ C_1) {
  int z = blockIdx.z;
  const float* PT = z ? PT1p : PT0;
  const float* mu = z ? mu_1 : mu_0;
  float* C = z ? C_1 : C_0;
  __shared__ float As[16][33];
  __shared__ float Bs[32][128];
  int t = threadIdx.x;
  int r0 = blockIdx.x * 16, k0 = blockIdx.y * 256;
  int tr = t >> 5, tc = t & 31;
  float4 acc0 = {0, 0, 0, 0}, acc1 = {0, 0, 0, 0};
  for (int kt = 0; kt < 256; kt += 32) {
    {
      int e = t, ar = e >> 5, ac = e & 31;
      As[ar][ac] = PT[(r0 + ar) * N + k0 + kt + ac];
      e = t + 256; ar = e >> 5; ac = e & 31;
      As[ar][ac] = PT[(r0 + ar) * N + k0 + kt + ac];
    }
#pragma unroll
    for (int i = 0; i < 4; i++) {
      int e = t + i * 256, br = e >> 5, bc = e & 31;
      *(float4*)&Bs[br][bc * 4] = *(const float4*)&mu[(k0 + kt + br) * M + bc * 4];
    }
    __syncthreads();
#pragma unroll
    for (int kk = 0; kk < 32; kk++) {
      float a0 = As[tr * 2][kk], a1 = As[tr * 2 + 1][kk];
      float4 b = *(const float4*)&Bs[kk][tc * 4];
      acc0.x = fmaf(a0, b.x, acc0.x); acc0.y = fmaf(a0, b.y, acc0.y);
      acc0.z = fmaf(a0, b.z, acc0.z); acc0.w = fmaf(a0, b.w, acc0.w);
      acc1.x = fmaf(a1, b.x, acc1.x); acc1.y = fmaf(a1, b.y, acc1.y);
      acc1.z = fmaf(a1, b.z, acc1.z); acc1.w = fmaf(a1, b.w, acc1.w);
    }
    __syncthreads();
  }
  float* dst = C + ((size_t)blockIdx.y * N + r0 + tr * 2) * M + tc * 4;
  *(float4*)dst = acc0;
  *(float4*)(dst + M) = acc1;
}

// ---------------- epilogue: reduce partials, second matmul, relu ----------------
// mode A: out = relu(Csum @ W3T[1:,:] + (wd*relu(muold@Wg))*W3T[0,:] + dist*W4c)
// mode B: out = relu(Csum @ W3T + bias)
__global__ __launch_bounds__(256) void k_epi(int modeA,
    const float* __restrict__ Cp_0, const float* __restrict__ muold_0,
    const float* __restrict__ wd_0, const float* __restrict__ dist_0,
    const float* __restrict__ W3T_0, const float* __restrict__ W4c_0,
    const float* __restrict__ Wg_0, float* __restrict__ out_0,
    const float* __restrict__ Cp_1, const float* __restrict__ muold_1,
    const float* __restrict__ wd_1, const float* __restrict__ dist_1,
    const float* __restrict__ W3T_1, const float* __restrict__ W4c_1,
    const float* __restrict__ Wg_1, float* __restrict__ out_1,
    const float* __restrict__ bias) {
  int z = blockIdx.z;
  const float* Cp = z ? Cp_1 : Cp_0;
  const float* muold = z ? muold_1 : muold_0;
  const float* wd = z ? wd_1 : wd_0;
  const float* dist = z ? dist_1 : dist_0;
  const float* W3T = z ? W3T_1 : W3T_0;
  const float* W4c = z ? W4c_1 : W4c_0;
  const float* Wg = z ? Wg_1 : Wg_0;
  float* out = z ? out_1 : out_0;

  __shared__ float Cs[16][129];
  __shared__ float swd[16];
  int t = threadIdx.x, r0 = blockIdx.x * 16;
#pragma unroll
  for (int i = 0; i < 8; i++) {
    int e = t + i * 256, r = e >> 7, m = e & 127;
    float s = 0.f;
#pragma unroll
    for (int c = 0; c < 4; c++) s += Cp[((size_t)c * N + r0 + r) * M + m];
    Cs[r][m] = s;
  }
  if (modeA) {
    int row = t >> 4, g = t & 15;
    float sp = 0.f;
    const float* mo = muold + (r0 + row) * M + g * 8;
#pragma unroll
    for (int j = 0; j < 8; j++) sp = fmaf(mo[j], Wg[g * 8 + j], sp);
#pragma unroll
    for (int o = 8; o; o >>= 1) sp += __shfl_xor(sp, o);
    if (g == 0) swd[row] = wd[r0 + row] * fmaxf(sp, 0.f);
  }
  __syncthreads();
  int tr = t >> 5, tc = t & 31;
  float4 acc0 = {0, 0, 0, 0}, acc1 = {0, 0, 0, 0};
  int off = modeA ? 1 : 0;
#pragma unroll 4
  for (int m = 0; m < 128; m++) {
    float a0 = Cs[tr * 2][m], a1 = Cs[tr * 2 + 1][m];
    float4 wv = *(const float4*)&W3T[(m + off) * 128 + tc * 4];
    acc0.x = fmaf(a0, wv.x, acc0.x); acc0.y = fmaf(a0, wv.y, acc0.y);
    acc0.z = fmaf(a0, wv.z, acc0.z); acc0.w = fmaf(a0, wv.w, acc0.w);
    acc1.x = fmaf(a1, wv.x, acc1.x); acc1.y = fmaf(a1, wv.y, acc1.y);
    acc1.z = fmaf(a1, wv.z, acc1.z); acc1.w = fmaf(a1, wv.w, acc1.w);
  }
  int ra = r0 + tr * 2, rb = ra + 1;
  float4 e0, e1;
  if (modeA) {
    float4 w30 = *(const float4*)&W3T[tc * 4];
    float4 w4v = *(const float4*)&W4c[tc * 4];
    float s0 = swd[tr * 2], s1 = swd[tr * 2 + 1];
    float d0 = dist[ra], d1 = dist[rb];
    e0.x = s0 * w30.x + d0 * w4v.x; e0.y = s0 * w30.y + d0 * w4v.y;
    e0.z = s0 * w30.z + d0 * w4v.z; e0.w = s0 * w30.w + d0 * w4v.w;
    e1.x = s1 * w30.x + d1 * w4v.x; e1.y = s1 * w30.y + d1 * w4v.y;
    e1.z = s1 * w30.z + d1 * w4v.z; e1.w = s1 * w30.w + d1 * w4v.w;
  } else {
    e0 = *(const float4*)&bias[ra * M + tc * 4];
    e1 = *(const float4*)&bias[rb * M + tc * 4];
  }
  float4 o0, o1;
  o0.x = fmaxf(acc0.x + e0.x, 0.f); o0.y = fmaxf(acc0.y + e0.y, 0.f);
  o0.z = fmaxf(acc0.z + e0.z, 0.f); o0.w = fmaxf(acc0.w + e0.w, 0.f);
  o1.x = fmaxf(acc1.x + e1.x, 0.f); o1.y = fmaxf(acc1.y + e1.y, 0.f);
  o1.z = fmaxf(acc1.z + e1.z, 0.f); o1.w = fmaxf(acc1.w + e1.w, 0.f);
  *(float4*)&out[ra * M + tc * 4] = o0;
  *(float4*)&out[rb * M + tc * 4] = o1;
}

// ---------------- bias = [A1, A2] @ W4_B.T ----------------
__global__ __launch_bounds__(256) void k_bias(const float* __restrict__ A1,
                                              const float* __restrict__ A2,
                                              const float* __restrict__ W4BT,
                                              float* __restrict__ bias) {
  __shared__ float Cs[16][257];
  int t = threadIdx.x, r0 = blockIdx.x * 16;
#pragma unroll
  for (int i = 0; i < 16; i++) {
    int e = t + i * 256, r = e >> 8, c = e & 255;
    Cs[r][c] = (c < 128) ? A1[(r0 + r) * M + c] : A2[(r0 + r) * M + (c - 128)];
  }
  __syncthreads();
  int tr = t >> 5, tc = t & 31;
  float4 acc0 = {0, 0, 0, 0}, acc1 = {0, 0, 0, 0};
#pragma unroll 4
  for (int m = 0; m < 256; m++) {
    float a0 = Cs[tr * 2][m], a1 = Cs[tr * 2 + 1][m];
    float4 wv = *(const float4*)&W4BT[m * 128 + tc * 4];
    acc0.x = fmaf(a0, wv.x, acc0.x); acc0.y = fmaf(a0, wv.y, acc0.y);
    acc0.z = fmaf(a0, wv.z, acc0.z); acc0.w = fmaf(a0, wv.w, acc0.w);
    acc1.x = fmaf(a1, wv.x, acc1.x); acc1.y = fmaf(a1, wv.y, acc1.y);
    acc1.z = fmaf(a1, wv.z, acc1.z); acc1.w = fmaf(a1, wv.w, acc1.w);
  }
  int ra = r0 + tr * 2, rb = ra + 1;
  *(float4*)&bias[ra * M + tc * 4] = acc0;
  *(float4*)&bias[rb * M + tc * 4] = acc1;
}

// ---------------- final: relu(W7 . colsum(mu)) ----------------
__global__ __launch_bounds__(1024) void k_final(const float* __restrict__ mu,
                                                const float* __restrict__ W7,
                                                float* __restrict__ out) {
  __shared__ float red[1024];
  int t = threadIdx.x;
  int j = t & 127, q = t >> 7;  // 8 slices
  float acc = 0.f;
  for (int v = q; v < N; v += 8) acc += mu[v * M + j];
  red[t] = acc;
  __syncthreads();
  float tot = 0.f;
  if (t < 128) {
    float cs = 0.f;
#pragma unroll
    for (int s = 0; s < 8; s++) cs += red[s * 128 + t];
    tot = cs * W7[t];
#pragma unroll
    for (int o = 32; o; o >>= 1) tot += __shfl_xor(tot, o);
  }
  __syncthreads();
  if (t == 0) red[0] = tot;
  if (t == 64) red[1] = tot;
  __syncthreads();
  if (t == 0) out[0] = fmaxf(red[0] + red[1], 0.f);
}

extern "C" void kernel_launch(void* const* d_in, const int* in_sizes, int n_in,
                              void* d_out, int out_size, void* d_ws, size_t ws_size,
                              hipStream_t stream) {
  (void)in_sizes; (void)n_in; (void)out_size; (void)ws_size;
  const float* D     = (const float*)d_in[0];
  const float* dd    = (const float*)d_in[1];
  const float* dr    = (const float*)d_in[2];
  const float* ddep  = (const float*)d_in[3];
  const float* mu0A1 = (const float*)d_in[4];
  const float* mu0A2 = (const float*)d_in[5];
  const float* mu0B  = (const float*)d_in[6];
  const float* W1    = (const float*)d_in[7];
  const float* W2    = (const float*)d_in[8];
  const float* W3A1  = (const float*)d_in[9];
  const float* W3A2  = (const float*)d_in[10];
  const float* W4A1  = (const float*)d_in[11];
  const float* W4A2  = (const float*)d_in[12];
  const float* W3B   = (const float*)d_in[13];
  const float* W4B   = (const float*)d_in[14];
  const float* W5    = (const float*)d_in[15];
  const float* W6    = (const float*)d_in[16];
  const float* W7    = (const float*)d_in[17];

  float* w = (float*)d_ws;
  size_t o = 0;
  auto alloc = [&](size_t n) { float* p = w + o; o += n; return p; };
  float* DT  = alloc((size_t)N * N);  // overlaid with Cp0/Cp1 (used only before iterations)
  float* Cp0 = DT;                    // 4*N*M floats
  float* Cp1 = DT + 4 * N * M;        // 4*N*M floats
  float* PT1 = alloc((size_t)N * N);
  float* PT2 = alloc((size_t)N * N);
  float* wd1 = alloc(N);
  float* wd2 = alloc(N);
  float* W3A1T = alloc(129 * 128);
  float* W3A2T = alloc(129 * 128);
  float* W3BT  = alloc(128 * 128);
  float* W4BT  = alloc(256 * 128);
  float* muA1a = alloc((size_t)N * M); float* muA1b = alloc((size_t)N * M);
  float* muA2a = alloc((size_t)N * M); float* muA2b = alloc((size_t)N * M);
  float* muBa  = alloc((size_t)N * M); float* muBb  = alloc((size_t)N * M);
  float* biasb = alloc((size_t)N * M);

  k_transpose_d<<<dim3(32, 32), dim3(32, 8), 0, stream>>>(D, DT);
  k_prep_w<<<4, 256, 0, stream>>>(W3A1, W3A2, W3B, W4B, W3A1T, W3A2T, W3BT, W4BT);
  k_edge<<<N, 256, 0, stream>>>(DT, dd, W1, W2, PT1, PT2, wd1, wd2);

  const float* cur1 = mu0A1;
  const float* cur2 = mu0A2;
  float* b1[2] = {muA1a, muA1b};
  float* b2[2] = {muA2a, muA2b};
  for (int t = 0; t < 4; t++) {
    k_gemm<<<dim3(64, 4, 2), 256, 0, stream>>>(PT1, cur1, Cp0, PT2, cur2, Cp1);
    k_epi<<<dim3(64, 1, 2), 256, 0, stream>>>(1,
        Cp0, cur1, wd1, dr,   W3A1T, W4A1, W5, b1[t & 1],
        Cp1, cur2, wd2, ddep, W3A2T, W4A2, W6, b2[t & 1], (const float*)nullptr);
    cur1 = b1[t & 1];
    cur2 = b2[t & 1];
  }
  k_bias<<<64, 256, 0, stream>>>(cur1, cur2, W4BT, biasb);

  const float* curB = mu0B;
  float* bB[2] = {muBa, muBb};
  for (int t = 0; t < 4; t++) {
    k_gemm<<<dim3(64, 4, 1), 256, 0, stream>>>(PT1, curB, Cp0, PT1, curB, Cp0);
    k_epi<<<dim3(64, 1, 1), 256, 0, stream>>>(0,
        Cp0, (const float*)nullptr, (const float*)nullptr, (const float*)nullptr,
        W3BT, (const float*)nullptr, (const float*)nullptr, bB[t & 1],
        (const float*)nullptr, (const float*)nullptr, (const float*)nullptr, (const float*)nullptr,
        (const float*)nullptr, (const float*)nullptr, (const float*)nullptr, (float*)nullptr,
        biasb);
    curB = bB[t & 1];
  }
  k_final<<<1, 1024, 0, stream>>>(curB, W7, (float*)d_out);
}

// Round 2
// 271.229 us; speedup vs baseline: 1.1136x; 1.1136x over previous
//
#include <hip/hip_runtime.h>
#include <math.h>

#define N 1024
#define M 128

// ---------------- transpose D (1024x1024) ----------------
__global__ __launch_bounds__(256) void k_transpose_d(const float* __restrict__ D,
                                                     float* __restrict__ DT) {
  __shared__ float tile[32][33];
  int tx = threadIdx.x, ty = threadIdx.y;
  int bx = blockIdx.x * 32, by = blockIdx.y * 32;
#pragma unroll
  for (int i = 0; i < 4; i++)
    tile[ty + i * 8][tx] = D[(by + ty + i * 8) * N + bx + tx];
  __syncthreads();
#pragma unroll
  for (int i = 0; i < 4; i++)
    DT[(bx + ty + i * 8) * N + by + tx] = tile[tx][ty + i * 8];
}

// ---------------- transpose small weight matrices (1 elem/thread, coalesced writes) ----------------
__global__ __launch_bounds__(256) void k_prep_w(const float* __restrict__ W3A1, const float* __restrict__ W3A2,
                         const float* __restrict__ W3B, const float* __restrict__ W4B,
                         float* __restrict__ oA1, float* __restrict__ oA2,
                         float* __restrict__ oB, float* __restrict__ o4B) {
  int idx = blockIdx.x * 256 + threadIdx.x;
  const float* in; float* out; int cols; int o;
  if (idx < 16512)      { in = W3A1; out = oA1; cols = 129; o = idx; }
  else if (idx < 33024) { in = W3A2; out = oA2; cols = 129; o = idx - 16512; }
  else if (idx < 49408) { in = W3B;  out = oB;  cols = 128; o = idx - 33024; }
  else if (idx < 82176) { in = W4B;  out = o4B; cols = 256; o = idx - 49408; }
  else return;
  // out[c*128 + r] = in[r*cols + c]; output-coalesced: o = c*128 + r
  int r = o & 127, c = o >> 7;
  out[o] = in[r * cols + c];
}

// ---------------- block reductions ----------------
__device__ __forceinline__ float blk_max(float v, float* red) {
#pragma unroll
  for (int o = 32; o; o >>= 1) v = fmaxf(v, __shfl_xor(v, o));
  __syncthreads();
  if ((threadIdx.x & 63) == 0) red[threadIdx.x >> 6] = v;
  __syncthreads();
  return fmaxf(fmaxf(red[0], red[1]), fmaxf(red[2], red[3]));
}
__device__ __forceinline__ float blk_sum(float v, float* red) {
#pragma unroll
  for (int o = 32; o; o >>= 1) v += __shfl_xor(v, o);
  __syncthreads();
  if ((threadIdx.x & 63) == 0) red[threadIdx.x >> 6] = v;
  __syncthreads();
  return red[0] + red[1] + red[2] + red[3];
}

// ---------------- edge scores + dual softmax + wd ----------------
// Block v: g[u] = G_raw[u,v]; G_scaled = g/1000 exactly (relu pos. homogeneous).
__global__ __launch_bounds__(256) void k_edge(const float* __restrict__ DT,
                                              const float* __restrict__ dd,
                                              const float* __restrict__ W1,
                                              const float* __restrict__ W2,
                                              float* __restrict__ PT1, float* __restrict__ PT2,
                                              float* __restrict__ wd1, float* __restrict__ wd2) {
  __shared__ float4 wp[128];
  __shared__ float red[4];
  int t = threadIdx.x, v = blockIdx.x;
  if (t < 128) {
    float4 p;
    p.x = W2[t * 3 + 0]; p.y = W2[t * 3 + 1]; p.z = W2[t * 3 + 2]; p.w = W1[t];
    wp[t] = p;
  }
  __syncthreads();
  float yv = dd[v];
  float x[4], z[4], g[4] = {0.f, 0.f, 0.f, 0.f};
#pragma unroll
  for (int i = 0; i < 4; i++) {
    int u = t + i * 256;
    x[i] = DT[v * N + u];
    z[i] = dd[u];
  }
#pragma unroll 2
  for (int k = 0; k < 128; k++) {
    float4 wk = wp[k];
    float cv = yv * wk.z;
#pragma unroll
    for (int i = 0; i < 4; i++) {
      float h = fmaf(x[i], wk.x, fmaf(z[i], wk.y, cv));
      g[i] = fmaf(fmaxf(h, 0.f), wk.w, g[i]);
    }
  }
#pragma unroll
  for (int i = 0; i < 4; i++)
    if (t + i * 256 == v) g[i] = -INFINITY;

  float m = fmaxf(fmaxf(g[0], g[1]), fmaxf(g[2], g[3]));
  m = blk_max(m, red);
  float er[4], es[4], sr = 0.f, ss = 0.f;
#pragma unroll
  for (int i = 0; i < 4; i++) {
    er[i] = expf((g[i] - m) * 0.1f);     // raw: /TAU
    es[i] = expf((g[i] - m) * 1e-4f);    // scaled: /(1000*TAU)
    sr += er[i]; ss += es[i];
  }
  sr = blk_sum(sr, red);
  ss = blk_sum(ss, red);
  float ir = 1.f / sr, is = 1.f / ss;
  float a1 = 0.f, a2 = 0.f;
#pragma unroll
  for (int i = 0; i < 4; i++) {
    int u = t + i * 256;
    float pr = er[i] * ir, ps = es[i] * is;
    PT2[v * N + u] = pr;
    PT1[v * N + u] = ps;
    a1 += ps * x[i];
    a2 += pr * x[i];
  }
  a1 = blk_sum(a1, red);
  a2 = blk_sum(a2, red);
  if (t == 0) { wd1[v] = a1; wd2[v] = a2; }
}

// ---------------- split-K GEMM: C_part[kc] = PT[rows, kchunk] @ mu[kchunk, :] ----------------
// grid (64, 4, nz): 16 rows/block, K-chunk 256. As stored k-major -> b64 broadcast per kk.
__global__ __launch_bounds__(256) void k_gemm(const float* __restrict__ PT0, const float* __restrict__ mu_0, float* __restrict__ C_0,
                                              const float* __restrict__ PT1p, const float* __restrict__ mu_1, float* __restrict__ C_1) {
  int z = blockIdx.z;
  const float* PT = z ? PT1p : PT0;
  const float* mu = z ? mu_1 : mu_0;
  float* C = z ? C_1 : C_0;
  __shared__ float As[32][18];   // k-major: As[kk][r], 16 rows, pad 18 (even -> b64 aligned)
  __shared__ float Bs[32][128];
  int t = threadIdx.x;
  int r0 = blockIdx.x * 16, k0 = blockIdx.y * 256;
  int tr = t >> 5, tc = t & 31;
  int lr = t >> 4, lk = t & 15;  // A-tile staging: row lr, k-offsets lk, lk+16
  float4 acc0 = {0, 0, 0, 0}, acc1 = {0, 0, 0, 0};
  for (int kt = 0; kt < 256; kt += 32) {
    const float* psrc = &PT[(r0 + lr) * N + k0 + kt + lk];
    float a0 = psrc[0], a1 = psrc[16];
#pragma unroll
    for (int i = 0; i < 4; i++) {
      int e = t + i * 256, br = e >> 5, bc = e & 31;
      *(float4*)&Bs[br][bc * 4] = *(const float4*)&mu[(k0 + kt + br) * M + bc * 4];
    }
    As[lk][lr] = a0;
    As[lk + 16][lr] = a1;
    __syncthreads();
#pragma unroll
    for (int kk = 0; kk < 32; kk++) {
      float2 av = *(const float2*)&As[kk][tr * 2];
      float4 b = *(const float4*)&Bs[kk][tc * 4];
      acc0.x = fmaf(av.x, b.x, acc0.x); acc0.y = fmaf(av.x, b.y, acc0.y);
      acc0.z = fmaf(av.x, b.z, acc0.z); acc0.w = fmaf(av.x, b.w, acc0.w);
      acc1.x = fmaf(av.y, b.x, acc1.x); acc1.y = fmaf(av.y, b.y, acc1.y);
      acc1.z = fmaf(av.y, b.z, acc1.z); acc1.w = fmaf(av.y, b.w, acc1.w);
    }
    __syncthreads();
  }
  float* dst = C + ((size_t)blockIdx.y * N + r0 + tr * 2) * M + tc * 4;
  *(float4*)dst = acc0;
  *(float4*)(dst + M) = acc1;
}

// ---------------- epilogue: reduce partials, second matmul, relu ----------------
// 8 rows/block, 128 blocks.
// mode A: out = relu(Csum @ W3T[1:,:] + (wd*relu(muold@Wg))*W3T[0,:] + dist*W4c)
// mode B: out = relu(Csum @ W3T + bias)
__global__ __launch_bounds__(256) void k_epi(int modeA,
    const float* __restrict__ Cp_0, const float* __restrict__ muold_0,
    const float* __restrict__ wd_0, const float* __restrict__ dist_0,
    const float* __restrict__ W3T_0, const float* __restrict__ W4c_0,
    const float* __restrict__ Wg_0, float* __restrict__ out_0,
    const float* __restrict__ Cp_1, const float* __restrict__ muold_1,
    const float* __restrict__ wd_1, const float* __restrict__ dist_1,
    const float* __restrict__ W3T_1, const float* __restrict__ W4c_1,
    const float* __restrict__ Wg_1, float* __restrict__ out_1,
    const float* __restrict__ bias) {
  int z = blockIdx.z;
  const float* Cp = z ? Cp_1 : Cp_0;
  const float* muold = z ? muold_1 : muold_0;
  const float* wd = z ? wd_1 : wd_0;
  const float* dist = z ? dist_1 : dist_0;
  const float* W3T = z ? W3T_1 : W3T_0;
  const float* W4c = z ? W4c_1 : W4c_0;
  const float* Wg = z ? Wg_1 : Wg_0;
  float* out = z ? out_1 : out_0;

  __shared__ float Cs[8][129];
  __shared__ float swd[8];
  int t = threadIdx.x, r0 = blockIdx.x * 8;
#pragma unroll
  for (int i = 0; i < 4; i++) {
    int e = t + i * 256, r = e >> 7, m = e & 127;
    float s = 0.f;
#pragma unroll
    for (int c = 0; c < 4; c++) s += Cp[((size_t)c * N + r0 + r) * M + m];
    Cs[r][m] = s;
  }
  if (modeA) {
    int row = t >> 5, g = t & 31;
    const float* mo = muold + (r0 + row) * M + g * 4;
    float sp = 0.f;
#pragma unroll
    for (int j = 0; j < 4; j++) sp = fmaf(mo[j], Wg[g * 4 + j], sp);
#pragma unroll
    for (int o = 16; o; o >>= 1) sp += __shfl_xor(sp, o);
    if (g == 0) swd[row] = wd[r0 + row] * fmaxf(sp, 0.f);
  }
  __syncthreads();
  int tr = t >> 5, tc = t & 31;
  float4 acc = {0, 0, 0, 0};
  int off = modeA ? 1 : 0;
#pragma unroll 8
  for (int m = 0; m < 128; m++) {
    float a = Cs[tr][m];
    float4 wv = *(const float4*)&W3T[(m + off) * 128 + tc * 4];
    acc.x = fmaf(a, wv.x, acc.x); acc.y = fmaf(a, wv.y, acc.y);
    acc.z = fmaf(a, wv.z, acc.z); acc.w = fmaf(a, wv.w, acc.w);
  }
  int ra = r0 + tr;
  float4 e0;
  if (modeA) {
    float4 w30 = *(const float4*)&W3T[tc * 4];
    float4 w4v = *(const float4*)&W4c[tc * 4];
    float s0 = swd[tr];
    float d0 = dist[ra];
    e0.x = s0 * w30.x + d0 * w4v.x; e0.y = s0 * w30.y + d0 * w4v.y;
    e0.z = s0 * w30.z + d0 * w4v.z; e0.w = s0 * w30.w + d0 * w4v.w;
  } else {
    e0 = *(const float4*)&bias[ra * M + tc * 4];
  }
  float4 o0;
  o0.x = fmaxf(acc.x + e0.x, 0.f); o0.y = fmaxf(acc.y + e0.y, 0.f);
  o0.z = fmaxf(acc.z + e0.z, 0.f); o0.w = fmaxf(acc.w + e0.w, 0.f);
  *(float4*)&out[ra * M + tc * 4] = o0;
}

// ---------------- bias = [A1, A2] @ W4_B.T ----------------
__global__ __launch_bounds__(256) void k_bias(const float* __restrict__ A1,
                                              const float* __restrict__ A2,
                                              const float* __restrict__ W4BT,
                                              float* __restrict__ bias) {
  __shared__ float Cs[16][257];
  int t = threadIdx.x, r0 = blockIdx.x * 16;
#pragma unroll
  for (int i = 0; i < 16; i++) {
    int e = t + i * 256, r = e >> 8, c = e & 255;
    Cs[r][c] = (c < 128) ? A1[(r0 + r) * M + c] : A2[(r0 + r) * M + (c - 128)];
  }
  __syncthreads();
  int tr = t >> 5, tc = t & 31;
  float4 acc0 = {0, 0, 0, 0}, acc1 = {0, 0, 0, 0};
#pragma unroll 4
  for (int m = 0; m < 256; m++) {
    float a0 = Cs[tr * 2][m], a1 = Cs[tr * 2 + 1][m];
    float4 wv = *(const float4*)&W4BT[m * 128 + tc * 4];
    acc0.x = fmaf(a0, wv.x, acc0.x); acc0.y = fmaf(a0, wv.y, acc0.y);
    acc0.z = fmaf(a0, wv.z, acc0.z); acc0.w = fmaf(a0, wv.w, acc0.w);
    acc1.x = fmaf(a1, wv.x, acc1.x); acc1.y = fmaf(a1, wv.y, acc1.y);
    acc1.z = fmaf(a1, wv.z, acc1.z); acc1.w = fmaf(a1, wv.w, acc1.w);
  }
  int ra = r0 + tr * 2, rb = ra + 1;
  *(float4*)&bias[ra * M + tc * 4] = acc0;
  *(float4*)&bias[rb * M + tc * 4] = acc1;
}

// ---------------- final: relu(W7 . colsum(mu)) ----------------
__global__ __launch_bounds__(1024) void k_final(const float* __restrict__ mu,
                                                const float* __restrict__ W7,
                                                float* __restrict__ out) {
  __shared__ float red[1024];
  int t = threadIdx.x;
  int j = t & 127, q = t >> 7;  // 8 slices
  float acc = 0.f;
  for (int v = q; v < N; v += 8) acc += mu[v * M + j];
  red[t] = acc;
  __syncthreads();
  float tot = 0.f;
  if (t < 128) {
    float cs = 0.f;
#pragma unroll
    for (int s = 0; s < 8; s++) cs += red[s * 128 + t];
    tot = cs * W7[t];
#pragma unroll
    for (int o = 32; o; o >>= 1) tot += __shfl_xor(tot, o);
  }
  __syncthreads();
  if (t == 0) red[0] = tot;
  if (t == 64) red[1] = tot;
  __syncthreads();
  if (t == 0) out[0] = fmaxf(red[0] + red[1], 0.f);
}

extern "C" void kernel_launch(void* const* d_in, const int* in_sizes, int n_in,
                              void* d_out, int out_size, void* d_ws, size_t ws_size,
                              hipStream_t stream) {
  (void)in_sizes; (void)n_in; (void)out_size; (void)ws_size;
  const float* D     = (const float*)d_in[0];
  const float* dd    = (const float*)d_in[1];
  const float* dr    = (const float*)d_in[2];
  const float* ddep  = (const float*)d_in[3];
  const float* mu0A1 = (const float*)d_in[4];
  const float* mu0A2 = (const float*)d_in[5];
  const float* mu0B  = (const float*)d_in[6];
  const float* W1    = (const float*)d_in[7];
  const float* W2    = (const float*)d_in[8];
  const float* W3A1  = (const float*)d_in[9];
  const float* W3A2  = (const float*)d_in[10];
  const float* W4A1  = (const float*)d_in[11];
  const float* W4A2  = (const float*)d_in[12];
  const float* W3B   = (const float*)d_in[13];
  const float* W4B   = (const float*)d_in[14];
  const float* W5    = (const float*)d_in[15];
  const float* W6    = (const float*)d_in[16];
  const float* W7    = (const float*)d_in[17];

  float* w = (float*)d_ws;
  size_t o = 0;
  auto alloc = [&](size_t n) { float* p = w + o; o += n; return p; };
  float* DT  = alloc((size_t)N * N);  // overlaid with Cp0/Cp1 (used only before iterations)
  float* Cp0 = DT;                    // 4*N*M floats
  float* Cp1 = DT + 4 * N * M;        // 4*N*M floats
  float* PT1 = alloc((size_t)N * N);
  float* PT2 = alloc((size_t)N * N);
  float* wd1 = alloc(N);
  float* wd2 = alloc(N);
  float* W3A1T = alloc(129 * 128);
  float* W3A2T = alloc(129 * 128);
  float* W3BT  = alloc(128 * 128);
  float* W4BT  = alloc(256 * 128);
  float* muA1a = alloc((size_t)N * M); float* muA1b = alloc((size_t)N * M);
  float* muA2a = alloc((size_t)N * M); float* muA2b = alloc((size_t)N * M);
  float* muBa  = alloc((size_t)N * M); float* muBb  = alloc((size_t)N * M);
  float* biasb = alloc((size_t)N * M);

  k_transpose_d<<<dim3(32, 32), dim3(32, 8), 0, stream>>>(D, DT);
  k_prep_w<<<321, 256, 0, stream>>>(W3A1, W3A2, W3B, W4B, W3A1T, W3A2T, W3BT, W4BT);
  k_edge<<<N, 256, 0, stream>>>(DT, dd, W1, W2, PT1, PT2, wd1, wd2);

  const float* cur1 = mu0A1;
  const float* cur2 = mu0A2;
  float* b1[2] = {muA1a, muA1b};
  float* b2[2] = {muA2a, muA2b};
  for (int t = 0; t < 4; t++) {
    k_gemm<<<dim3(64, 4, 2), 256, 0, stream>>>(PT1, cur1, Cp0, PT2, cur2, Cp1);
    k_epi<<<dim3(128, 1, 2), 256, 0, stream>>>(1,
        Cp0, cur1, wd1, dr,   W3A1T, W4A1, W5, b1[t & 1],
        Cp1, cur2, wd2, ddep, W3A2T, W4A2, W6, b2[t & 1], (const float*)nullptr);
    cur1 = b1[t & 1];
    cur2 = b2[t & 1];
  }
  k_bias<<<64, 256, 0, stream>>>(cur1, cur2, W4BT, biasb);

  const float* curB = mu0B;
  float* bB[2] = {muBa, muBb};
  for (int t = 0; t < 4; t++) {
    k_gemm<<<dim3(64, 4, 1), 256, 0, stream>>>(PT1, curB, Cp0, PT1, curB, Cp0);
    k_epi<<<dim3(128, 1, 1), 256, 0, stream>>>(0,
        Cp0, (const float*)nullptr, (const float*)nullptr, (const float*)nullptr,
        W3BT, (const float*)nullptr, (const float*)nullptr, bB[t & 1],
        (const float*)nullptr, (const float*)nullptr, (const float*)nullptr, (const float*)nullptr,
        (const float*)nullptr, (const float*)nullptr, (const float*)nullptr, (float*)nullptr,
        biasb);
    curB = bB[t & 1];
  }
  k_final<<<1, 1024, 0, stream>>>(curB, W7, (float*)d_out);
}